// Round 7
// baseline (143.356 us; speedup 1.0000x reference)
//
#include <hip/hip_runtime.h>

#define HH 128
#define WW 128
#define HW (HH * WW)
#define CIN 64
#define COUT 64

// ws layout (bytes):
//   xT  : [0, 16777216)       bf16 NHWC [b8][y128][x128][c64]
//   Bf  : [+0, 49152)         main-conv B-frags bf16 [pk6][kc2][nt4][lane64][j8]
//   OBf : [+49152, +18432)    offset-conv B-frags bf16 [s18][lane64][j8]
#define XT_OFF  0
#define BF_OFF  16777216
#define OBF_OFF (BF_OFF + 49152)

typedef short bf16x8 __attribute__((ext_vector_type(8)));
typedef float f32x4 __attribute__((ext_vector_type(4)));

__device__ __forceinline__ unsigned short f2bf(float f) {     // RNE (prep/repack)
    union { float f; unsigned int u; } v; v.f = f;
    unsigned int r = v.u + 0x7FFFu + ((v.u >> 16) & 1u);
    return (unsigned short)(r >> 16);
}
__device__ __forceinline__ unsigned short f2bf_up(float f) {  // round-half-up (hot path)
    union { float f; unsigned int u; } v; v.f = f;
    return (unsigned short)((v.u + 0x8000u) >> 16);
}
__device__ __forceinline__ float bf2f(unsigned short u) {
    union { unsigned int u; float f; } v; v.u = ((unsigned int)u) << 16;
    return v.f;
}

// -------------------------------------------------------------------------
// Kernel 1 (merged): blocks [0,1024) repack x NCHW fp32 -> xT NHWC bf16;
// blocks [1024,1156) build bf16 B-fragments for both matmuls.
// -------------------------------------------------------------------------
__global__ __launch_bounds__(256) void prep_repack_kernel(const float* __restrict__ x,
                                                          const float* __restrict__ ow,
                                                          const float* __restrict__ wh,
                                                          const float* __restrict__ wv,
                                                          unsigned short* __restrict__ xT,
                                                          unsigned short* __restrict__ Bf,
                                                          unsigned short* __restrict__ OBf) {
    __shared__ float tile[64 * 129];
    const int tid = threadIdx.x;
    const int blk = blockIdx.x;

    if (blk < 1024) {
        // ---- repack one (b, y) row ----
        const int b = blk & 7;
        const int y = blk >> 3;
        const float* xb = x + (size_t)b * CIN * HW + y * WW;
        const int tx = tid & 127;
        const int th = tid >> 7;
        for (int c0 = 0; c0 < 64; c0 += 2) {
            int c = c0 + th;
            tile[c * 129 + tx] = xb[(size_t)c * HW + tx];
        }
        __syncthreads();
        unsigned short* ob = xT + ((size_t)b * HW + y * WW) * 64;
#pragma unroll
        for (int it = 0; it < 4; ++it) {
            int e  = it * 256 + tid;
            int h  = e & 7;
            int px = e >> 3;
            union { unsigned short us[8]; uint4 u4; } pkd;
#pragma unroll
            for (int j = 0; j < 8; ++j)
                pkd.us[j] = f2bf(tile[(h * 8 + j) * 129 + px]);
            *(uint4*)&ob[px * 64 + h * 8] = pkd.u4;
        }
    } else {
        // ---- weight fragments ----
        int i = (blk - 1024) * 256 + tid;
        if (i < 24576) {
            int j    = i & 7;
            int lane = (i >> 3) & 63;
            int nt   = (i >> 9) & 3;
            int kc   = (i >> 11) & 1;
            int pk   = i >> 12;                    // ph*3+k
            int o = nt * 16 + (lane & 15);
            int c = kc * 32 + (lane >> 4) * 8 + j;
            int k = pk % 3;
            const float* src = (pk < 3) ? wh : wv; // both flatten as (O,C,3)
            Bf[i] = f2bf(src[(o * CIN + c) * 3 + k]);
        } else if (i < 24576 + 9216) {
            int mI   = i - 24576;
            int j    = mI & 7;
            int lane = (mI >> 3) & 63;
            int s    = mI >> 9;                    // 0..17
            int n    = lane & 15;
            int q    = lane >> 4;
            int c    = (s & 1) * 32 + q * 8 + j;
            int tap  = s >> 1;
            int dy   = tap / 3, dx = tap % 3;
            OBf[mI] = (n < 6) ? f2bf(ow[((n * CIN + c) * 3 + dy) * 3 + dx])
                              : (unsigned short)0;
        }
    }
}

// -------------------------------------------------------------------------
// Fused kernel. 2048 blocks = b(8 low bits: XCD pin) x y(128) x xh(2).
// Block = 4 waves; wave = 16 px x 64 outs (8192 waves total = 32/CU by
// grid; launch_bounds(256,6) -> ~24 resident). All tap metadata is
// precomputed into registers before the gather/MFMA loop so the 24 A-loads
// issue without interleaved dependent address math.
// -------------------------------------------------------------------------
__global__ __launch_bounds__(256, 6) void fused_kernel(const unsigned short* __restrict__ xT,
                                                       const float* __restrict__ obias,
                                                       const unsigned short* __restrict__ Bf,
                                                       const unsigned short* __restrict__ OBf,
                                                       float* __restrict__ out) {
    __shared__ float offT[4 * 16 * 8];       // [w][px16][pk pad8] 2 KB

    const int tid  = threadIdx.x;
    const int w    = tid >> 6;
    const int lane = tid & 63;
    const int q    = lane >> 4;
    const int m    = lane & 15;

    const int blk = blockIdx.x;              // b(8) x y(128) x xh(2)
    const int b   = blk & 7;
    const int y   = (blk >> 3) & 127;
    const int xh  = blk >> 10;
    const int x0w = (xh << 6) + (w << 4);    // wave's 16-col strip

    const unsigned short* xtb = xT + (size_t)b * HW * 64;

    // ---------- phase 1: offset conv (3x3, Cin=64 -> 6) ----------
    f32x4 acc6 = {0.f, 0.f, 0.f, 0.f};
#pragma unroll
    for (int s = 0; s < 18; ++s) {
        const int tap  = s >> 1;
        const int dy   = tap / 3 - 1;
        const int dx   = tap % 3 - 1;
        const int coff = (s & 1) * 32 + q * 8;
        int yy = y + dy;
        int xx = x0w + m + dx;
        bool ok = (yy >= 0) && (yy < HH) && (xx >= 0) && (xx < WW);
        int yc = min(max(yy, 0), HH - 1);
        int xc = min(max(xx, 0), WW - 1);
        uint4 raw = *(const uint4*)&xtb[(size_t)(yc * WW + xc) * 64 + coff];
        if (!ok) raw = make_uint4(0, 0, 0, 0);
        union { uint4 u4; bf16x8 v; } af; af.u4 = raw;
        bf16x8 bfr = *(const bf16x8*)&OBf[(s * 64 + lane) * 8];
        acc6 = __builtin_amdgcn_mfma_f32_16x16x32_bf16(af.v, bfr, acc6, 0, 0, 0);
    }
    // C layout: row(px)=q*4+reg, col(j)=m. Transpose via LDS.
    if (m < 6) {
        float bias = obias[m];
#pragma unroll
        for (int reg = 0; reg < 4; ++reg)
            offT[(w * 16 + q * 4 + reg) * 8 + m] = acc6[reg] + bias;
    }
    __syncthreads();
    f32x4  o03 = *(const f32x4*)&offT[(w * 16 + m) * 8];
    float2 o45 = *(const float2*)&offT[(w * 16 + m) * 8 + 4];
    float offs[6] = {o03[0], o03[1], o03[2], o03[3], o45.x, o45.y};

    // ---------- phase 2 metadata: all 6 taps up-front ----------
    const int xs = x0w + m;
    float wA[6], wB[6];
    int   iA[6], iB[6];
#pragma unroll
    for (int pk = 0; pk < 6; ++pk) {
        const int ph = pk / 3;
        const int k  = pk % 3;
        float o1 = offs[pk];
        if (ph == 0) {
            // horizontal: py = y + off (frac), px = xs + k - 1 (int)
            float py  = (float)y + o1;
            float y0f = floorf(py);
            float wy  = py - y0f;
            int   yi  = (int)y0f;
            bool v0 = (yi >= 0) && (yi <= HH - 1);
            bool v1 = (yi + 1 >= 0) && (yi + 1 <= HH - 1);
            int  pxx = xs + k - 1;
            bool pv  = (pxx >= 0) && (pxx <= WW - 1);
            wA[pk] = (pv && v0) ? (1.f - wy) : 0.f;
            wB[pk] = (pv && v1) ? wy : 0.f;
            int ra = min(max(yi, 0), HH - 1);
            int rb = min(max(yi + 1, 0), HH - 1);
            int ca = min(max(pxx, 0), WW - 1);
            iA[pk] = ra * WW + ca;
            iB[pk] = rb * WW + ca;
        } else {
            // vertical: py = y + k - 1 (int), px = xs + off (frac)
            float pxf = (float)xs + o1;
            float x0f = floorf(pxf);
            float wx  = pxf - x0f;
            int   xi  = (int)x0f;
            bool v0 = (xi >= 0) && (xi <= WW - 1);
            bool v1 = (xi + 1 >= 0) && (xi + 1 <= WW - 1);
            int  py = y + k - 1;
            bool pv = (py >= 0) && (py <= HH - 1);
            wA[pk] = (pv && v0) ? (1.f - wx) : 0.f;
            wB[pk] = (pv && v1) ? wx : 0.f;
            int ra  = min(max(py, 0), HH - 1);
            int ca  = min(max(xi, 0), WW - 1);
            int cb2 = min(max(xi + 1, 0), WW - 1);
            iA[pk] = ra * WW + ca;
            iB[pk] = ra * WW + cb2;
        }
    }

    // ---------- phase 2: gather + lerp + MFMA ----------
    f32x4 acc[4];
#pragma unroll
    for (int nt = 0; nt < 4; ++nt) acc[nt] = (f32x4){0.f, 0.f, 0.f, 0.f};

#pragma unroll
    for (int pk = 0; pk < 6; ++pk) {
#pragma unroll
        for (int kc = 0; kc < 2; ++kc) {
            const int coff = kc * 32 + q * 8;
            union { uint4 u4; unsigned short us[8]; } ua, ub;
            ua.u4 = *(const uint4*)&xtb[(size_t)iA[pk] * 64 + coff];
            ub.u4 = *(const uint4*)&xtb[(size_t)iB[pk] * 64 + coff];
            union { unsigned short us[8]; bf16x8 v; } uf;
#pragma unroll
            for (int j = 0; j < 8; ++j) {
                float v = wA[pk] * bf2f(ua.us[j]) + wB[pk] * bf2f(ub.us[j]);
                uf.us[j] = f2bf_up(v);
            }
#pragma unroll
            for (int nt = 0; nt < 4; ++nt) {
                bf16x8 bfr = *(const bf16x8*)&Bf[(((pk * 2 + kc) * 4 + nt) * 64 + lane) * 8];
                acc[nt] = __builtin_amdgcn_mfma_f32_16x16x32_bf16(uf.v, bfr, acc[nt], 0, 0, 0);
            }
        }
    }

    // ---------- epilogue: C row(px)=q*4+reg, col(o)=m ----------
#pragma unroll
    for (int nt = 0; nt < 4; ++nt) {
        int o = nt * 16 + m;
        float* op = out + ((size_t)(b * COUT + o) * HH + y) * WW + x0w + q * 4;
        *(f32x4*)op = acc[nt];
    }
}

extern "C" void kernel_launch(void* const* d_in, const int* in_sizes, int n_in,
                              void* d_out, int out_size, void* d_ws, size_t ws_size,
                              hipStream_t stream) {
    const float* x     = (const float*)d_in[0];
    const float* ow    = (const float*)d_in[1];
    const float* obias = (const float*)d_in[2];
    const float* wh    = (const float*)d_in[3];
    const float* wv    = (const float*)d_in[4];
    float* out = (float*)d_out;

    char* ws = (char*)d_ws;
    unsigned short* xT  = (unsigned short*)(ws + XT_OFF);
    unsigned short* Bf  = (unsigned short*)(ws + BF_OFF);
    unsigned short* OBf = (unsigned short*)(ws + OBF_OFF);

    // blocks [0,1024): repack; [1024,1156): weight prep
    prep_repack_kernel<<<dim3(1156), dim3(256), 0, stream>>>(x, ow, wh, wv, xT, Bf, OBf);
    // 2048 blocks = b(8, XCD-pin) x y(128) x xh(2); 4 waves x 16 px
    fused_kernel<<<dim3(2048), dim3(256), 0, stream>>>(xT, obias, Bf, OBf, out);
}

// Round 8
// 137.696 us; speedup vs baseline: 1.0411x; 1.0411x over previous
//
#include <hip/hip_runtime.h>

#define HH 128
#define WW 128
#define HW (HH * WW)
#define CIN 64
#define COUT 64

// ws layout (bytes):
//   xT  : [0, 16777216)       bf16 NHWC [b8][y128][x128][c64]
//   Bf  : [+0, 49152)         main-conv B-frags bf16 [pk6][kc2][nt4][lane64][j8]
//   OBf : [+49152, +18432)    offset-conv B-frags bf16 [s18][lane64][j8]
#define XT_OFF  0
#define BF_OFF  16777216
#define OBF_OFF (BF_OFF + 49152)

typedef short bf16x8 __attribute__((ext_vector_type(8)));
typedef float f32x4 __attribute__((ext_vector_type(4)));

__device__ __forceinline__ unsigned short f2bf(float f) {     // RNE (prep/repack)
    union { float f; unsigned int u; } v; v.f = f;
    unsigned int r = v.u + 0x7FFFu + ((v.u >> 16) & 1u);
    return (unsigned short)(r >> 16);
}
__device__ __forceinline__ unsigned short f2bf_up(float f) {  // round-half-up (hot path)
    union { float f; unsigned int u; } v; v.f = f;
    return (unsigned short)((v.u + 0x8000u) >> 16);
}
__device__ __forceinline__ float bf2f(unsigned short u) {
    union { unsigned int u; float f; } v; v.u = ((unsigned int)u) << 16;
    return v.f;
}

// -------------------------------------------------------------------------
// Kernel 1 (merged): blocks [0,1024) repack x NCHW fp32 -> xT NHWC bf16;
// blocks [1024,1156) build bf16 B-fragments for both matmuls.
// -------------------------------------------------------------------------
__global__ __launch_bounds__(256) void prep_repack_kernel(const float* __restrict__ x,
                                                          const float* __restrict__ ow,
                                                          const float* __restrict__ wh,
                                                          const float* __restrict__ wv,
                                                          unsigned short* __restrict__ xT,
                                                          unsigned short* __restrict__ Bf,
                                                          unsigned short* __restrict__ OBf) {
    __shared__ float tile[64 * 129];
    const int tid = threadIdx.x;
    const int blk = blockIdx.x;

    if (blk < 1024) {
        // ---- repack one (b, y) row ----
        const int b = blk & 7;
        const int y = blk >> 3;
        const float* xb = x + (size_t)b * CIN * HW + y * WW;
        const int tx = tid & 127;
        const int th = tid >> 7;
        for (int c0 = 0; c0 < 64; c0 += 2) {
            int c = c0 + th;
            tile[c * 129 + tx] = xb[(size_t)c * HW + tx];
        }
        __syncthreads();
        unsigned short* ob = xT + ((size_t)b * HW + y * WW) * 64;
#pragma unroll
        for (int it = 0; it < 4; ++it) {
            int e  = it * 256 + tid;
            int h  = e & 7;
            int px = e >> 3;
            union { unsigned short us[8]; uint4 u4; } pkd;
#pragma unroll
            for (int j = 0; j < 8; ++j)
                pkd.us[j] = f2bf(tile[(h * 8 + j) * 129 + px]);
            *(uint4*)&ob[px * 64 + h * 8] = pkd.u4;
        }
    } else {
        // ---- weight fragments ----
        int i = (blk - 1024) * 256 + tid;
        if (i < 24576) {
            int j    = i & 7;
            int lane = (i >> 3) & 63;
            int nt   = (i >> 9) & 3;
            int kc   = (i >> 11) & 1;
            int pk   = i >> 12;                    // ph*3+k
            int o = nt * 16 + (lane & 15);
            int c = kc * 32 + (lane >> 4) * 8 + j;
            int k = pk % 3;
            const float* src = (pk < 3) ? wh : wv; // both flatten as (O,C,3)
            Bf[i] = f2bf(src[(o * CIN + c) * 3 + k]);
        } else if (i < 24576 + 9216) {
            int mI   = i - 24576;
            int j    = mI & 7;
            int lane = (mI >> 3) & 63;
            int s    = mI >> 9;                    // 0..17 = tap*2 + chalf
            int n    = lane & 15;
            int q    = lane >> 4;
            int c    = (s & 1) * 32 + q * 8 + j;
            int tap  = s >> 1;
            int dy   = tap / 3, dx = tap % 3;
            OBf[mI] = (n < 6) ? f2bf(ow[((n * CIN + c) * 3 + dy) * 3 + dx])
                              : (unsigned short)0;
        }
    }
}

// -------------------------------------------------------------------------
// Fused kernel. 2048 blocks = b(8, XCD pin) x y(128) x xh(2); 4 waves x
// 16 px x 64 outs. KEY (r8): all gather loads batch-issued into register
// arrays before consumption (launch_bounds(256,3) -> ~170 VGPR budget, ~24
// loads in flight per wave); main B-fragments staged in LDS once per block
// (reuses the one barrier) so L1 serves only the A-gathers.
// -------------------------------------------------------------------------
__global__ __launch_bounds__(256, 3) void fused_kernel(const unsigned short* __restrict__ xT,
                                                       const float* __restrict__ obias,
                                                       const unsigned short* __restrict__ Bf,
                                                       const unsigned short* __restrict__ OBf,
                                                       float* __restrict__ out) {
    __shared__ unsigned short BfL[24576];    // 48 KB main-conv B-frags
    __shared__ float offT[4 * 16 * 8];       // [w][px16][pk pad8] 2 KB

    const int tid  = threadIdx.x;
    const int w    = tid >> 6;
    const int lane = tid & 63;
    const int q    = lane >> 4;
    const int m    = lane & 15;

    const int blk = blockIdx.x;              // b(8) x y(128) x xh(2)
    const int b   = blk & 7;
    const int y   = (blk >> 3) & 127;
    const int xh  = blk >> 10;
    const int x0w = (xh << 6) + (w << 4);    // wave's 16-col strip

    const unsigned short* xtb = xT + (size_t)b * HW * 64;

    // ---- stage main B-frags to LDS (visible after the one barrier below) ----
#pragma unroll
    for (int i = 0; i < 12; ++i)
        *(uint4*)&BfL[(i * 256 + tid) * 8] = ((const uint4*)Bf)[i * 256 + tid];

    // ---------- phase 1: offset conv (3x3, Cin=64 -> 6), batched loads ----------
    f32x4 acc6 = {0.f, 0.f, 0.f, 0.f};
#pragma unroll
    for (int half = 0; half < 2; ++half) {
        const int coff = half * 32 + q * 8;
        uint4 r1[9];
        bool  okt[9];
#pragma unroll
        for (int tap = 0; tap < 9; ++tap) {
            int dy = tap / 3 - 1, dx = tap % 3 - 1;
            int yy = y + dy;
            int xx = x0w + m + dx;
            okt[tap] = (yy >= 0) && (yy < HH) && (xx >= 0) && (xx < WW);
            int yc = min(max(yy, 0), HH - 1);
            int xc = min(max(xx, 0), WW - 1);
            r1[tap] = *(const uint4*)&xtb[(size_t)(yc * WW + xc) * 64 + coff];
        }
#pragma unroll
        for (int tap = 0; tap < 9; ++tap) {
            uint4 raw = okt[tap] ? r1[tap] : make_uint4(0, 0, 0, 0);
            union { uint4 u4; bf16x8 v; } af; af.u4 = raw;
            bf16x8 bfr = *(const bf16x8*)&OBf[((tap * 2 + half) * 64 + lane) * 8];
            acc6 = __builtin_amdgcn_mfma_f32_16x16x32_bf16(af.v, bfr, acc6, 0, 0, 0);
        }
    }
    // C layout: row(px)=q*4+reg, col(j)=m. Transpose via LDS.
    if (m < 6) {
        float bias = obias[m];
#pragma unroll
        for (int reg = 0; reg < 4; ++reg)
            offT[(w * 16 + q * 4 + reg) * 8 + m] = acc6[reg] + bias;
    }
    __syncthreads();                         // covers offT AND BfL staging
    f32x4  o03 = *(const f32x4*)&offT[(w * 16 + m) * 8];
    float2 o45 = *(const float2*)&offT[(w * 16 + m) * 8 + 4];
    float offs[6] = {o03[0], o03[1], o03[2], o03[3], o45.x, o45.y};

    // ---------- phase 2 metadata: all 6 taps up-front ----------
    const int xs = x0w + m;
    float wA[6], wB[6];
    int   iA[6], iB[6];
#pragma unroll
    for (int pk = 0; pk < 6; ++pk) {
        const int ph = pk / 3;
        const int k  = pk % 3;
        float o1 = offs[pk];
        if (ph == 0) {
            // horizontal: py = y + off (frac), px = xs + k - 1 (int)
            float py  = (float)y + o1;
            float y0f = floorf(py);
            float wy  = py - y0f;
            int   yi  = (int)y0f;
            bool v0 = (yi >= 0) && (yi <= HH - 1);
            bool v1 = (yi + 1 >= 0) && (yi + 1 <= HH - 1);
            int  pxx = xs + k - 1;
            bool pv  = (pxx >= 0) && (pxx <= WW - 1);
            wA[pk] = (pv && v0) ? (1.f - wy) : 0.f;
            wB[pk] = (pv && v1) ? wy : 0.f;
            int ra = min(max(yi, 0), HH - 1);
            int rb = min(max(yi + 1, 0), HH - 1);
            int ca = min(max(pxx, 0), WW - 1);
            iA[pk] = ra * WW + ca;
            iB[pk] = rb * WW + ca;
        } else {
            // vertical: py = y + k - 1 (int), px = xs + off (frac)
            float pxf = (float)xs + o1;
            float x0f = floorf(pxf);
            float wx  = pxf - x0f;
            int   xi  = (int)x0f;
            bool v0 = (xi >= 0) && (xi <= WW - 1);
            bool v1 = (xi + 1 >= 0) && (xi + 1 <= WW - 1);
            int  py = y + k - 1;
            bool pv = (py >= 0) && (py <= HH - 1);
            wA[pk] = (pv && v0) ? (1.f - wx) : 0.f;
            wB[pk] = (pv && v1) ? wx : 0.f;
            int ra  = min(max(py, 0), HH - 1);
            int ca  = min(max(xi, 0), WW - 1);
            int cb2 = min(max(xi + 1, 0), WW - 1);
            iA[pk] = ra * WW + ca;
            iB[pk] = ra * WW + cb2;
        }
    }

    // ---------- phase 2: ALL 24 gather loads issued back-to-back ----------
    uint4 rA[12], rB[12];
#pragma unroll
    for (int pk = 0; pk < 6; ++pk) {
#pragma unroll
        for (int kc = 0; kc < 2; ++kc) {
            const int coff = kc * 32 + q * 8;
            rA[pk * 2 + kc] = *(const uint4*)&xtb[(size_t)iA[pk] * 64 + coff];
            rB[pk * 2 + kc] = *(const uint4*)&xtb[(size_t)iB[pk] * 64 + coff];
        }
    }

    // ---------- consume: lerp + pack + MFMA (B from LDS) ----------
    f32x4 acc[4];
#pragma unroll
    for (int nt = 0; nt < 4; ++nt) acc[nt] = (f32x4){0.f, 0.f, 0.f, 0.f};

#pragma unroll
    for (int pk = 0; pk < 6; ++pk) {
#pragma unroll
        for (int kc = 0; kc < 2; ++kc) {
            const int g = pk * 2 + kc;
            union { uint4 u4; unsigned short us[8]; } ua, ub;
            ua.u4 = rA[g];
            ub.u4 = rB[g];
            union { unsigned short us[8]; bf16x8 v; } uf;
#pragma unroll
            for (int j = 0; j < 8; ++j) {
                float v = wA[pk] * bf2f(ua.us[j]) + wB[pk] * bf2f(ub.us[j]);
                uf.us[j] = f2bf_up(v);
            }
#pragma unroll
            for (int nt = 0; nt < 4; ++nt) {
                bf16x8 bfr = *(const bf16x8*)&BfL[((g * 4 + nt) * 64 + lane) * 8];
                acc[nt] = __builtin_amdgcn_mfma_f32_16x16x32_bf16(uf.v, bfr, acc[nt], 0, 0, 0);
            }
        }
    }

    // ---------- epilogue: C row(px)=q*4+reg, col(o)=m ----------
#pragma unroll
    for (int nt = 0; nt < 4; ++nt) {
        int o = nt * 16 + m;
        float* op = out + ((size_t)(b * COUT + o) * HH + y) * WW + x0w + q * 4;
        *(f32x4*)op = acc[nt];
    }
}

extern "C" void kernel_launch(void* const* d_in, const int* in_sizes, int n_in,
                              void* d_out, int out_size, void* d_ws, size_t ws_size,
                              hipStream_t stream) {
    const float* x     = (const float*)d_in[0];
    const float* ow    = (const float*)d_in[1];
    const float* obias = (const float*)d_in[2];
    const float* wh    = (const float*)d_in[3];
    const float* wv    = (const float*)d_in[4];
    float* out = (float*)d_out;

    char* ws = (char*)d_ws;
    unsigned short* xT  = (unsigned short*)(ws + XT_OFF);
    unsigned short* Bf  = (unsigned short*)(ws + BF_OFF);
    unsigned short* OBf = (unsigned short*)(ws + OBF_OFF);

    // blocks [0,1024): repack; [1024,1156): weight prep
    prep_repack_kernel<<<dim3(1156), dim3(256), 0, stream>>>(x, ow, wh, wv, xT, Bf, OBf);
    // 2048 blocks = b(8, XCD-pin) x y(128) x xh(2); 4 waves x 16 px
    fused_kernel<<<dim3(2048), dim3(256), 0, stream>>>(xT, obias, Bf, OBf, out);
}